// Round 6
// baseline (110.158 us; speedup 1.0000x reference)
//
#include <hip/hip_runtime.h>
#include <hip/hip_bf16.h>

// out[b,h,w,dy*9+dx] = leaky_relu( mean_c( prv[b,h,w,c] * nxt[b,h+dy-4,w+dx-4,c] ), 0.1 )
// Banded bf16 MFMA, R6: double-buffered LDS (1 barrier/kstep), non-draining barrier
// (loads for k+1 stay in flight across it), and per-block k-phase stagger to
// decorrelate co-resident blocks' memory stalls.

#define B_ 8
#define H_ 128
#define W_ 128
#define C_ 192
#define ND 9
#define NDISP 81
#define HT 4            // output rows per block (one per wave)
#define WT 16           // output cols per block
#define KS 32           // channels per k-step
#define NK 6            // 192/32
#define BROWS 12        // HT + ND - 1 nxt rows staged
#define BCOLS 24        // WT + 8 nxt cols staged
#define APX (HT * WT)          // 64 prv pixels
#define BPX (BROWS * BCOLS)    // 288 nxt pixels
#define ACH (4 * APX)          // 256 16B A-chunks per kstep
#define BCH (4 * BPX)          // 1152 16B B-chunks per kstep
#define TCH (ACH + BCH)        // 1408
#define NSLOT 6                // ceil(TCH/256); slot 5 covers tid<128 only

typedef short short8 __attribute__((ext_vector_type(8)));
typedef float f32x4 __attribute__((ext_vector_type(4)));

static __device__ __forceinline__ short bf1(float f) {
    __hip_bfloat16 h = __float2bfloat16(f);   // pairs fuse to v_cvt_pk_bf16_f32
    return __builtin_bit_cast(short, h);
}

static __device__ __forceinline__ short8 cvt8(float4 x, float4 y) {
    short8 v;
    v[0] = bf1(x.x); v[1] = bf1(x.y); v[2] = bf1(x.z); v[3] = bf1(x.w);
    v[4] = bf1(y.x); v[5] = bf1(y.y); v[6] = bf1(y.z); v[7] = bf1(y.w);
    return v;
}

// LDS-fence + barrier WITHOUT vmcnt drain: outstanding global loads stay in flight.
static __device__ __forceinline__ void barrier_no_vm_drain() {
    asm volatile("s_waitcnt lgkmcnt(0)\n\ts_barrier" ::: "memory");
}

__global__ __launch_bounds__(256, 3)
void cv_mfma(const float* __restrict__ prv, const float* __restrict__ nxt,
             float* __restrict__ out) {
    // LDS: [buf][c-chunk][pixel][8 bf16]; frag reads = contiguous 256B runs, conflict-free.
    __shared__ short8 sm[2][TCH];   // 45 KB -> 3 blocks/CU

    const int tid = threadIdx.x;
    const int w0 = blockIdx.x * WT;
    const int h0 = blockIdx.y * HT;
    const int b  = blockIdx.z;

    const int lane = tid & 63;
    const int wid  = tid >> 6;      // 0..3: wave handles output row h0+wid
    const int lq = lane & 15;
    const int lc = lane >> 4;

    // k-phase stagger: co-resident blocks (different b / tile) start at different ks
    int ks = (blockIdx.x + blockIdx.y + blockIdx.z) % NK;

    // ---- hoisted staging slots (k-step adds a constant 128B offset)
    const float* gp[NSLOT];
    bool ok[NSLOT];
#pragma unroll
    for (int i = 0; i < NSLOT; ++i) {
        const int idx = tid + i * 256;
        ok[i] = false;
        gp[i] = prv;                 // dummy, never dereferenced when !ok
        if (idx < TCH) {
            if (idx < ACH) {         // A: prv[h0+r][w0+p], always in range
                const int c = idx >> 6;
                const int px = idx & (APX - 1);
                const int r = px >> 4;
                const int p = px & 15;
                gp[i] = prv + (size_t)(((b * H_ + h0 + r) * W_ + w0 + p)) * C_ + c * 8;
                ok[i] = true;
            } else {                 // B: nxt[h0-4+row][w0-4+col]
                const int t = idx - ACH;
                const int c = t / BPX;
                const int rem = t - c * BPX;
                const int row = rem / BCOLS;
                const int col = rem - row * BCOLS;
                const int gh = h0 - 4 + row;
                const int gw = w0 - 4 + col;
                ok[i] = ((unsigned)gh < (unsigned)H_) && ((unsigned)gw < (unsigned)W_);
                gp[i] = nxt + (long long)((b * H_ + gh) * W_ + gw) * C_ + c * 8;
            }
        }
    }

    // ---- staging registers; OOB slots stay zero forever (cvt8(0)=0)
    float4 x[NSLOT], y[NSLOT];
#pragma unroll
    for (int i = 0; i < NSLOT; ++i) {
        x[i] = make_float4(0.f, 0.f, 0.f, 0.f);
        y[i] = x[i];
    }

    // prologue: issue loads for the first (staggered) k-step
#pragma unroll
    for (int i = 0; i < NSLOT; ++i) {
        if (ok[i]) {
            const float* p = gp[i] + ks * KS;
            x[i] = *(const float4*)p;
            y[i] = *(const float4*)(p + 4);
        }
    }

    f32x4 acc[ND][2];
#pragma unroll
    for (int d = 0; d < ND; ++d) {
        acc[d][0] = (f32x4){0.f, 0.f, 0.f, 0.f};
        acc[d][1] = (f32x4){0.f, 0.f, 0.f, 0.f};
    }

    for (int it = 0; it < NK; ++it) {
        short8* buf = sm[it & 1];

        // ---- write step-ks regs to this iteration's buffer
        //      (compiler inserts the vmcnt wait for these regs' loads here)
#pragma unroll
        for (int i = 0; i < NSLOT - 1; ++i)
            buf[tid + i * 256] = cvt8(x[i], y[i]);
        if (tid < TCH - (NSLOT - 1) * 256)     // wave-uniform (tid<128: waves 0,1)
            buf[tid + (NSLOT - 1) * 256] = cvt8(x[NSLOT - 1], y[NSLOT - 1]);

        // ---- issue next step's loads; they stay in flight across the barrier
        int ksn = ks + 1; if (ksn == NK) ksn = 0;
        if (it + 1 < NK) {
#pragma unroll
            for (int i = 0; i < NSLOT; ++i) {
                if (ok[i]) {
                    const float* p = gp[i] + ksn * KS;
                    x[i] = *(const float4*)p;
                    y[i] = *(const float4*)(p + 4);
                }
            }
        }
        ks = ksn;

        barrier_no_vm_drain();   // LDS visible to all waves; global loads NOT drained

        // ---- compute: 9 dy x 2 overlapping col-tiles from buf
        const short8 a0 = buf[lc * APX + wid * WT + lq];
#pragma unroll
        for (int dy = 0; dy < ND; ++dy) {
            const int base = ACH + lc * BPX + (wid + dy) * BCOLS + lq;
            const short8 b0 = buf[base];       // cols w0-4+q
            const short8 b1 = buf[base + 8];   // cols w0+4+q
            acc[dy][0] = __builtin_amdgcn_mfma_f32_16x16x32_bf16(a0, b0, acc[dy][0], 0, 0, 0);
            acc[dy][1] = __builtin_amdgcn_mfma_f32_16x16x32_bf16(a0, b1, acc[dy][1], 0, 0, 0);
        }
        // NOTE: no trailing barrier needed — next iteration writes the OTHER buffer,
        // and the write after the NEXT barrier can't start until all waves passed it.
    }

    // ---- epilogue: D layout col=lane&15, row=4*(lane>>4)+reg (verified m89/m91)
    // rows r<8 valid in tile0 (dx=q-r), rows r>=8 in tile1 (dx=q-r+8). Static acc index
    // per branch (rule #20: no runtime indexing into ext_vector arrays).
    const float inv = 1.0f / (float)C_;
    const int h = h0 + wid;
    if (lc < 2) {
#pragma unroll
        for (int rg = 0; rg < 4; ++rg) {
            const int r = 4 * lc + rg;
            const int dx = lq - r;
            if (dx >= 0 && dx <= 8) {
                float* o = out + (size_t)((b * H_ + h) * W_ + w0 + r) * NDISP + dx;
#pragma unroll
                for (int dy = 0; dy < ND; ++dy) {
                    const float v = acc[dy][0][rg] * inv;
                    o[dy * ND] = v >= 0.f ? v : 0.1f * v;
                }
            }
        }
    } else {
#pragma unroll
        for (int rg = 0; rg < 4; ++rg) {
            const int r = 4 * lc + rg;
            const int dx = lq - r + 8;
            if (dx >= 0 && dx <= 8) {
                float* o = out + (size_t)((b * H_ + h) * W_ + w0 + r) * NDISP + dx;
#pragma unroll
                for (int dy = 0; dy < ND; ++dy) {
                    const float v = acc[dy][1][rg] * inv;
                    o[dy * ND] = v >= 0.f ? v : 0.1f * v;
                }
            }
        }
    }
}

extern "C" void kernel_launch(void* const* d_in, const int* in_sizes, int n_in,
                              void* d_out, int out_size, void* d_ws, size_t ws_size,
                              hipStream_t stream) {
    const float* prv = (const float*)d_in[0];
    const float* nxt = (const float*)d_in[1];
    float* out = (float*)d_out;

    dim3 grid(W_ / WT, H_ / HT, B_);   // (8, 32, 8) = 2048 blocks
    cv_mfma<<<grid, 256, 0, stream>>>(prv, nxt, out);
}